// Round 3
// baseline (448.223 us; speedup 1.0000x reference)
//
#include <hip/hip_runtime.h>

// ModernBertAttention fused pipeline, bf16 MFMA (16x16x32), fp32 I/O.
// B=4 S=2048 H=1024 NH=16 D=64.

typedef __bf16 bf16x8 __attribute__((ext_vector_type(8)));
typedef float f32x4 __attribute__((ext_vector_type(4)));
typedef unsigned short u16x8 __attribute__((ext_vector_type(8)));
typedef const __attribute__((address_space(1))) void* gptr_t;
typedef __attribute__((address_space(3))) void* lptr_t;

__device__ __forceinline__ unsigned short f2bf(float f) {
  union { float f; unsigned u; } v; v.f = f;
  unsigned r = (v.u + 0x7fffu + ((v.u >> 16) & 1u)) >> 16;  // RNE
  return (unsigned short)r;
}

__device__ __forceinline__ unsigned short f2bfn(float f) {
  union { __bf16 h; unsigned short u; } v;
  v.h = (__bf16)f;  // native v_cvt
  return v.u;
}

__device__ __forceinline__ void gld16(const void* g, void* l) {
  __builtin_amdgcn_global_load_lds((gptr_t)g, (lptr_t)l, 16, 0, 0);
}

// f32 -> bf16, 8 elems/thread
__global__ __launch_bounds__(256) void cvt_bf16(const float* __restrict__ src,
                                                unsigned short* __restrict__ dst,
                                                int n8) {
  int i = blockIdx.x * 256 + threadIdx.x;
  if (i >= n8) return;
  const float4* s = (const float4*)src;
  float4 a = s[(size_t)i * 2], b = s[(size_t)i * 2 + 1];
  u16x8 o;
  o[0] = f2bf(a.x); o[1] = f2bf(a.y); o[2] = f2bf(a.z); o[3] = f2bf(a.w);
  o[4] = f2bf(b.x); o[5] = f2bf(b.y); o[6] = f2bf(b.z); o[7] = f2bf(b.w);
  *(u16x8*)(dst + (size_t)i * 8) = o;
}

// GEMM C[M,1024] = A[M,1024] * W[1024,1024]^T (both bf16, K contiguous).
// mode 0: write f32 to Cout.
// mode 1: blockIdx.z selects {Wq->Qh(+RoPE), Wk->Kh(+RoPE), Wv->Vh} head-major bf16.
// 128x128 tile, BK=64, 4 waves (each 64x64 = 4x4 frags of 16x16x32 MFMA).
__global__ __launch_bounds__(256, 2) void gemm_k(
    const unsigned short* __restrict__ A,
    const unsigned short* __restrict__ W0, const unsigned short* __restrict__ W1,
    const unsigned short* __restrict__ W2,
    const float* __restrict__ cosT, const float* __restrict__ sinT,
    unsigned short* __restrict__ Qh, unsigned short* __restrict__ Kh,
    unsigned short* __restrict__ Vh, float* __restrict__ Cout, int mode) {
  __shared__ char sm[32768];
  char* As = sm;
  char* Bs = sm + 16384;
  const int tid = threadIdx.x, lane = tid & 63, w = tid >> 6;
  const int wm = w >> 1, wn = w & 1;
  const int brow = blockIdx.y * 128;
  const int bcol = blockIdx.x * 128;
  const unsigned short* Wsel =
      (mode == 0) ? W0 : (blockIdx.z == 0 ? W0 : (blockIdx.z == 1 ? W1 : W2));

  f32x4 acc[4][4];
#pragma unroll
  for (int m = 0; m < 4; ++m)
#pragma unroll
    for (int n = 0; n < 4; ++n) acc[m][n] = (f32x4){0.f, 0.f, 0.f, 0.f};

  const char* Abase = (const char*)A + (size_t)brow * 2048;
  const char* Bbase = (const char*)Wsel + (size_t)bcol * 2048;

  for (int kt = 0; kt < 1024; kt += 64) {
    // stage A,B tiles [128 rows][64 bf16 =128B] linear LDS, source XOR-swizzled
#pragma unroll
    for (int c = 0; c < 4; ++c) {
      int Lb = w * 4096 + c * 1024;
      int L = Lb + lane * 16;
      int r = L >> 7, kb = L & 127;
      int sw = kb ^ ((r & 7) << 4);
      gld16(Abase + (size_t)r * 2048 + kt * 2 + sw, As + Lb);
      gld16(Bbase + (size_t)r * 2048 + kt * 2 + sw, Bs + Lb);
    }
    __syncthreads();
#pragma unroll
    for (int kk = 0; kk < 2; ++kk) {
      int kb = kk * 64 + (lane >> 4) * 16;
      bf16x8 af[4], bfr[4];
#pragma unroll
      for (int m = 0; m < 4; ++m) {
        int r = wm * 64 + m * 16 + (lane & 15);
        af[m] = *(const bf16x8*)(As + r * 128 + (kb ^ ((r & 7) << 4)));
      }
#pragma unroll
      for (int n = 0; n < 4; ++n) {
        int r = wn * 64 + n * 16 + (lane & 15);
        bfr[n] = *(const bf16x8*)(Bs + r * 128 + (kb ^ ((r & 7) << 4)));
      }
#pragma unroll
      for (int m = 0; m < 4; ++m)
#pragma unroll
        for (int n = 0; n < 4; ++n)
          acc[m][n] = __builtin_amdgcn_mfma_f32_16x16x32_bf16(af[m], bfr[n],
                                                              acc[m][n], 0, 0, 0);
    }
    __syncthreads();
  }

  if (mode == 0) {
#pragma unroll
    for (int m = 0; m < 4; ++m)
#pragma unroll
      for (int n = 0; n < 4; ++n)
#pragma unroll
        for (int i = 0; i < 4; ++i) {
          int row = brow + wm * 64 + m * 16 + (lane >> 4) * 4 + i;
          int col = bcol + wn * 64 + n * 16 + (lane & 15);
          Cout[(size_t)row * 1024 + col] = acc[m][n][i];
        }
  } else {
    const int z = blockIdx.z;
    unsigned short* dst = (z == 0) ? Qh : (z == 1 ? Kh : Vh);
    const int h = (bcol + wn * 64) >> 6;  // wave spans exactly one head
#pragma unroll
    for (int m = 0; m < 4; ++m)
#pragma unroll
      for (int i = 0; i < 4; ++i) {
        int row = brow + wm * 64 + m * 16 + (lane >> 4) * 4 + i;
        int b = row >> 11, s = row & 2047;
        size_t hb = ((size_t)(b * 16 + h) * 2048 + s) * 64;
        if (z == 2) {
#pragma unroll
          for (int n = 0; n < 4; ++n)
            dst[hb + n * 16 + (lane & 15)] = f2bf(acc[m][n][i]);
        } else {
          // RoPE: partner of d (<32) is d+32 = frag n+2, same lane.
#pragma unroll
          for (int n = 0; n < 2; ++n) {
            int dl = n * 16 + (lane & 15);
            float c = cosT[s * 64 + dl], sn = sinT[s * 64 + dl];
            float lo = acc[m][n][i], hi = acc[m][n + 2][i];
            dst[hb + dl] = f2bf(lo * c - hi * sn);
            dst[hb + dl + 32] = f2bf(hi * c + lo * sn);
          }
        }
      }
  }
}

// Flash attention v2: 128 q-rows/block (4 waves x 32), kv tile 64,
// double-buffered K (global_load_lds) + V (reg-staged transpose),
// single barrier per kv-iter (2-phase pipeline), native bf16 cvt.
__global__ __launch_bounds__(256, 3) void attn_k(
    const unsigned short* __restrict__ Q, const unsigned short* __restrict__ K,
    const unsigned short* __restrict__ V, const float* __restrict__ mask,
    unsigned short* __restrict__ O) {
  __shared__ char Ks[2][8192];
  __shared__ char Vs[2][9216];
  __shared__ char Ps[4][4096];
  const int tid = threadIdx.x, lane = tid & 63, w = tid >> 6;
  const int l15 = lane & 15, h2 = lane >> 4;
  const int h = blockIdx.y, b = blockIdx.z;
  const size_t hb = (size_t)(b * 16 + h) * (2048 * 64);
  const int q0 = blockIdx.x * 128 + w * 32;

  // Q fragments: 2 m-frags x 2 k-halves
  bf16x8 qa[2][2];
#pragma unroll
  for (int m = 0; m < 2; ++m) {
    const char* qrow =
        (const char*)(Q + hb + (size_t)(q0 + m * 16 + l15) * 64);
#pragma unroll
    for (int kk = 0; kk < 2; ++kk)
      qa[m][kk] = *(const bf16x8*)(qrow + kk * 64 + h2 * 16);
  }
  const float* maskb = mask + (size_t)b * 2048;
  const char* Kbase = (const char*)(K + hb);

  float m_run[2][4], l_run[2][4];
  f32x4 oacc[2][4];
#pragma unroll
  for (int m = 0; m < 2; ++m)
#pragma unroll
    for (int i = 0; i < 4; ++i) { m_run[m][i] = -1e30f; l_run[m][i] = 0.f; }
#pragma unroll
  for (int m = 0; m < 2; ++m)
#pragma unroll
    for (int n = 0; n < 4; ++n) oacc[m][n] = (f32x4){0.f, 0.f, 0.f, 0.f};

  const int kvp = tid >> 3, dseg = tid & 7;  // V staging decomposition
  u16x8 v0r, v1r;

  // ---- prologue: stage tile 0 ----
#pragma unroll
  for (int c = 0; c < 2; ++c) {
    int Lb = w * 2048 + c * 1024;
    int L = Lb + lane * 16;
    int r = L >> 7, kb = L & 127;
    gld16(Kbase + (size_t)r * 128 + (kb ^ ((r & 7) << 4)), Ks[0] + Lb);
  }
  {
    const char* vsrc = (const char*)(V + hb + (size_t)(kvp * 2) * 64) + dseg * 16;
    v0r = *(const u16x8*)(vsrc);
    v1r = *(const u16x8*)(vsrc + 128);
  }
#pragma unroll
  for (int j = 0; j < 8; ++j) {
    int d = dseg * 8 + j;
    unsigned pk = (unsigned)v0r[j] | ((unsigned)v1r[j] << 16);
    *(unsigned*)(Vs[0] + d * 144 + ((kvp * 4) ^ (dseg << 4))) = pk;
  }
  __syncthreads();

  for (int t = 0; t < 32; ++t) {
    const int cur = t & 1, nxt = cur ^ 1;
    const int kv0 = t * 64;
    // issue next tile's loads first (overlap with compute below)
    if (t < 31) {
      const int kvn = kv0 + 64;
#pragma unroll
      for (int c = 0; c < 2; ++c) {
        int Lb = w * 2048 + c * 1024;
        int L = Lb + lane * 16;
        int r = L >> 7, kb = L & 127;
        gld16(Kbase + (size_t)(kvn + r) * 128 + (kb ^ ((r & 7) << 4)),
              Ks[nxt] + Lb);
      }
      const char* vsrc =
          (const char*)(V + hb + (size_t)(kvn + kvp * 2) * 64) + dseg * 16;
      v0r = *(const u16x8*)(vsrc);
      v1r = *(const u16x8*)(vsrc + 128);
    }
    float mv[4];
#pragma unroll
    for (int n = 0; n < 4; ++n) mv[n] = maskb[kv0 + n * 16 + l15];

    // ---- QK^T: scores for 2 m-frags x 64 kv ----
    f32x4 sacc[2][4];
#pragma unroll
    for (int m = 0; m < 2; ++m)
#pragma unroll
      for (int n = 0; n < 4; ++n) sacc[m][n] = (f32x4){0.f, 0.f, 0.f, 0.f};
#pragma unroll
    for (int kk = 0; kk < 2; ++kk) {
      int kb = kk * 64 + h2 * 16;
      bf16x8 kf[4];
#pragma unroll
      for (int n = 0; n < 4; ++n) {
        int r = n * 16 + l15;
        kf[n] = *(const bf16x8*)(Ks[cur] + r * 128 + (kb ^ ((r & 7) << 4)));
      }
#pragma unroll
      for (int m = 0; m < 2; ++m)
#pragma unroll
        for (int n = 0; n < 4; ++n)
          sacc[m][n] = __builtin_amdgcn_mfma_f32_16x16x32_bf16(
              qa[m][kk], kf[n], sacc[m][n], 0, 0, 0);
    }

    // ---- online softmax per m-frag ----
#pragma unroll
    for (int m = 0; m < 2; ++m) {
      float sc[4][4];
#pragma unroll
      for (int n = 0; n < 4; ++n)
#pragma unroll
        for (int i = 0; i < 4; ++i) sc[n][i] = sacc[m][n][i] * 0.125f + mv[n];
      float mb[4], al[4], rs[4];
#pragma unroll
      for (int i = 0; i < 4; ++i)
        mb[i] = fmaxf(fmaxf(sc[0][i], sc[1][i]), fmaxf(sc[2][i], sc[3][i]));
#pragma unroll
      for (int d = 1; d < 16; d <<= 1)
#pragma unroll
        for (int i = 0; i < 4; ++i) mb[i] = fmaxf(mb[i], __shfl_xor(mb[i], d, 64));
#pragma unroll
      for (int i = 0; i < 4; ++i) {
        float nm = fmaxf(m_run[m][i], mb[i]);
        al[i] = __expf(m_run[m][i] - nm);
        m_run[m][i] = nm;
      }
#pragma unroll
      for (int n = 0; n < 4; ++n)
#pragma unroll
        for (int i = 0; i < 4; ++i) sc[n][i] = __expf(sc[n][i] - m_run[m][i]);
#pragma unroll
      for (int i = 0; i < 4; ++i) rs[i] = sc[0][i] + sc[1][i] + sc[2][i] + sc[3][i];
#pragma unroll
      for (int d = 1; d < 16; d <<= 1)
#pragma unroll
        for (int i = 0; i < 4; ++i) rs[i] += __shfl_xor(rs[i], d, 64);
#pragma unroll
      for (int i = 0; i < 4; ++i) l_run[m][i] = l_run[m][i] * al[i] + rs[i];
#pragma unroll
      for (int n = 0; n < 4; ++n)
#pragma unroll
        for (int i = 0; i < 4; ++i) oacc[m][n][i] *= al[i];
      // P -> per-wave LDS (D-layout -> A-layout)
#pragma unroll
      for (int n = 0; n < 4; ++n)
#pragma unroll
        for (int i = 0; i < 4; ++i) {
          int r = m * 16 + h2 * 4 + i;
          int cb = (n * 16 + l15) * 2;
          *(unsigned short*)(Ps[w] + r * 128 + (cb ^ ((r & 7) << 4))) =
              f2bfn(sc[n][i]);
        }
    }
    asm volatile("s_waitcnt lgkmcnt(0)" ::: "memory");
    __builtin_amdgcn_sched_barrier(0);

    // ---- PV ----
#pragma unroll
    for (int kvh = 0; kvh < 2; ++kvh) {
      int kvb = kvh * 64 + h2 * 16;
      bf16x8 vf[4];
#pragma unroll
      for (int n = 0; n < 4; ++n) {
        int dd = n * 16 + l15;
        vf[n] = *(const bf16x8*)(Vs[cur] + dd * 144 +
                                 (kvb ^ (((dd >> 3) & 7) << 4)));
      }
#pragma unroll
      for (int m = 0; m < 2; ++m) {
        int pr = m * 16 + l15;
        bf16x8 pa = *(const bf16x8*)(Ps[w] + pr * 128 + (kvb ^ ((pr & 7) << 4)));
#pragma unroll
        for (int n = 0; n < 4; ++n)
          oacc[m][n] = __builtin_amdgcn_mfma_f32_16x16x32_bf16(pa, vf[n],
                                                               oacc[m][n], 0, 0, 0);
      }
    }

    // V transpose-write for next tile, then the single barrier
    if (t < 31) {
#pragma unroll
      for (int j = 0; j < 8; ++j) {
        int d = dseg * 8 + j;
        unsigned pk = (unsigned)v0r[j] | ((unsigned)v1r[j] << 16);
        *(unsigned*)(Vs[nxt] + d * 144 + ((kvp * 4) ^ (dseg << 4))) = pk;
      }
    }
    __syncthreads();
  }

#pragma unroll
  for (int m = 0; m < 2; ++m)
#pragma unroll
    for (int i = 0; i < 4; ++i) {
      float inv = 1.0f / l_run[m][i];
      int row = b * 2048 + q0 + m * 16 + h2 * 4 + i;
      size_t rb = (size_t)row * 1024 + h * 64;
#pragma unroll
      for (int n = 0; n < 4; ++n)
        O[rb + n * 16 + l15] = f2bfn(oacc[m][n][i] * inv);
    }
}

extern "C" void kernel_launch(void* const* d_in, const int* in_sizes, int n_in,
                              void* d_out, int out_size, void* d_ws, size_t ws_size,
                              hipStream_t stream) {
  const float* hidden = (const float*)d_in[0];
  const float* amask = (const float*)d_in[1];
  const float* cosT = (const float*)d_in[2];
  const float* sinT = (const float*)d_in[3];
  const float* Wq = (const float*)d_in[4];
  const float* Wk = (const float*)d_in[5];
  const float* Wv = (const float*)d_in[6];
  const float* Wo = (const float*)d_in[7];
  float* out = (float*)d_out;

  // ws layout (bf16): Xb 8M | Wq,Wk,Wv,Wo 1M each | Qh,Kh,Vh,Ob 8M each = 88 MB
  if (ws_size < (size_t)92274688) return;
  unsigned short* Xb = (unsigned short*)d_ws;
  unsigned short* Wqb = Xb + (size_t)8192 * 1024;
  unsigned short* Wkb = Wqb + (size_t)1024 * 1024;
  unsigned short* Wvb = Wkb + (size_t)1024 * 1024;
  unsigned short* Wob = Wvb + (size_t)1024 * 1024;
  unsigned short* Qh = Wob + (size_t)1024 * 1024;
  unsigned short* Kh = Qh + (size_t)8388608;
  unsigned short* Vh = Kh + (size_t)8388608;
  unsigned short* Ob = Vh + (size_t)8388608;

  cvt_bf16<<<4096, 256, 0, stream>>>(hidden, Xb, 1048576);
  cvt_bf16<<<512, 256, 0, stream>>>(Wq, Wqb, 131072);
  cvt_bf16<<<512, 256, 0, stream>>>(Wk, Wkb, 131072);
  cvt_bf16<<<512, 256, 0, stream>>>(Wv, Wvb, 131072);
  cvt_bf16<<<512, 256, 0, stream>>>(Wo, Wob, 131072);

  gemm_k<<<dim3(8, 64, 3), 256, 0, stream>>>(Xb, Wqb, Wkb, Wvb, cosT, sinT, Qh, Kh,
                                             Vh, nullptr, 1);
  attn_k<<<dim3(16, 16, 4), 256, 0, stream>>>(Qh, Kh, Vh, amask, Ob);
  gemm_k<<<dim3(8, 64, 1), 256, 0, stream>>>(Ob, Wob, Wob, Wob, cosT, sinT, nullptr,
                                             nullptr, nullptr, out, 0);
}